// Round 6
// baseline (109.044 us; speedup 1.0000x reference)
//
#include <hip/hip_runtime.h>

typedef unsigned short u16;
typedef unsigned int u32;
typedef __attribute__((ext_vector_type(8))) __bf16 bf16x8;
typedef __attribute__((ext_vector_type(4))) float f32x4;
typedef __attribute__((ext_vector_type(4))) u32 u32x4;
typedef __attribute__((ext_vector_type(4))) u16 u16x4;

#define DEV __device__ __forceinline__

constexpr int S_LEN = 2048;
constexpr int DMODEL = 1024;
constexpr int NHEAD = 16;
constexpr int ROWS = 4096;   // B*S
// fold 1/sqrt(64) * log2(e) into Q so softmax is exp2(s - B), B = 16
constexpr float QSCALE = 0.125f * 1.4426950408889634f;

DEV u16 f2bf(float f) {
  union { float f; u32 u; } v; v.f = f;
  u32 u = v.u;
  u32 r = (u + 0x7fffu + ((u >> 16) & 1u)) >> 16;  // RNE
  return (u16)r;
}
DEV float vexp2(float x) {
#if __has_builtin(__builtin_amdgcn_exp2f)
  return __builtin_amdgcn_exp2f(x);
#else
  return exp2f(x);
#endif
}
// async global->LDS, 16B per lane (m97 recipe)
DEV void gload_lds16(const u16* g, u16* l) {
  __builtin_amdgcn_global_load_lds((const __attribute__((address_space(1))) void*)g,
                                   (__attribute__((address_space(3))) void*)l, 16, 0, 0);
}
// XOR swizzle for [rows][64] u16 LDS tiles (row stride 128B), 8-col granules
DEV int swz(int r, int c) { return r * 64 + (c ^ ((r & 7) << 3)); }

// ---------------- fused fp32 -> bf16 convert for x, w_qkv, w_out ----------------
__global__ __launch_bounds__(256) void k_cvt_all(const float* __restrict__ x,
                                                 const float* __restrict__ wq,
                                                 const float* __restrict__ wo,
                                                 u16* __restrict__ xb,
                                                 u16* __restrict__ wqb,
                                                 u16* __restrict__ wob) {
  int i = blockIdx.x * 256 + threadIdx.x;  // 1048576 total (x8 elems)
  const float* in; u16* out; int off;
  if (i < 524288)       { in = x;  out = xb;  off = i; }
  else if (i < 917504)  { in = wq; out = wqb; off = i - 524288; }
  else                  { in = wo; out = wob; off = i - 917504; }
  const float4* p4 = (const float4*)in;
  float4 a = p4[2 * off], b = p4[2 * off + 1];
  alignas(16) u16 r[8] = {f2bf(a.x), f2bf(a.y), f2bf(a.z), f2bf(a.w),
                          f2bf(b.x), f2bf(b.y), f2bf(b.z), f2bf(b.w)};
  *(u32x4*)(out + 8 * off) = *(const u32x4*)r;
}

// ---------------- RoPE cos/sin table: [S][32] float2 (cos, sin) ----------------
__global__ __launch_bounds__(256) void k_rope_tab(const int* __restrict__ pos,
                                                  float2* __restrict__ tab) {
  int t = blockIdx.x * 256 + threadIdx.x;  // S*32 = 65536
  int s = t >> 5, fi = t & 31;
  float p = (float)pos[s];
  float invf = expf(-(float)fi * 0.28782313662425572f);  // 10000^(-fi/32)
  float ang = p * invf;
  tab[t] = float2{cosf(ang), sinf(ang)};
}

// ================= GEMM template: 128x128, BK=64, 4 waves, dbuf ===============
// T3+T4: STAGE(t+1) -> vmcnt(8) (t landed, t+1 in flight) -> barrier ->
// COMPUTE(t) -> barrier. Next tile's loads stay in flight across both barriers.
// MODE 1 (QKV): cols<2048 -> RoPE(+QSCALE on q) fused -> bf16 qk[row][2048];
//               cols>=2048 -> V^T bf16 vt[(b*1024+hd)][s].
// MODE 0: fp32 out [M][1024].
template <int MODE>
__global__ __launch_bounds__(256, 2) void k_gemm(const u16* __restrict__ A,
                                                 const u16* __restrict__ Bw,
                                                 void* __restrict__ Out,
                                                 u16* __restrict__ vt,
                                                 const float2* __restrict__ tab,
                                                 int NB) {
  __shared__ alignas(16) u16 As[2][8192];  // [buf][128][64] swizzled
  __shared__ alignas(16) u16 Bs[2][8192];
  const int tid = threadIdx.x, lane = tid & 63;
  const int w = tid >> 6, wr = w >> 1, wc = w & 1;
  const int l15 = lane & 15, l16 = lane >> 4;
  // bijective XCD swizzle (grid multiple of 8)
  const int cpx = gridDim.x >> 3;
  const int wg = (blockIdx.x & 7) * cpx + (blockIdx.x >> 3);
  const int mb = wg / NB, nb = wg - mb * NB;
  const int m0 = mb * 128, n0 = nb * 128;

  // staging: 256 threads cover [128][64] in 4 chunks; involution granule swizzle
  const int sr = tid >> 3;
  const int swcol = ((tid & 7) ^ (sr & 7)) * 8;
  const u16* aT = A + (size_t)(m0 + sr) * 1024 + swcol;
  const u16* bT = Bw + (size_t)(n0 + sr) * 1024 + swcol;
  const int dst0 = tid * 8;

#define STAGE(bufc, t) do { \
    _Pragma("unroll") \
    for (int i_ = 0; i_ < 4; i_++) { \
      gload_lds16(aT + (size_t)(i_ * 32) * 1024 + (t) * 64, &As[bufc][dst0 + i_ * 2048]); \
      gload_lds16(bT + (size_t)(i_ * 32) * 1024 + (t) * 64, &Bs[bufc][dst0 + i_ * 2048]); \
    } \
  } while (0)

  f32x4 acc[4][4] = {};
  const int x7 = l15 & 7;

#define COMPUTE(bufc) do { \
    bf16x8 af_[4][2], bf_[4][2]; \
    _Pragma("unroll") \
    for (int m_ = 0; m_ < 4; m_++) \
      _Pragma("unroll") \
      for (int k_ = 0; k_ < 2; k_++) \
        af_[m_][k_] = *(const bf16x8*)&As[bufc][(wr * 64 + m_ * 16 + l15) * 64 + \
                                               (((k_ * 4 + l16) ^ x7) * 8)]; \
    _Pragma("unroll") \
    for (int n_ = 0; n_ < 4; n_++) \
      _Pragma("unroll") \
      for (int k_ = 0; k_ < 2; k_++) \
        bf_[n_][k_] = *(const bf16x8*)&Bs[bufc][(wc * 64 + n_ * 16 + l15) * 64 + \
                                               (((k_ * 4 + l16) ^ x7) * 8)]; \
    __builtin_amdgcn_s_setprio(1); \
    _Pragma("unroll") \
    for (int m_ = 0; m_ < 4; m_++) \
      _Pragma("unroll") \
      for (int n_ = 0; n_ < 4; n_++) \
        _Pragma("unroll") \
        for (int k_ = 0; k_ < 2; k_++) \
          acc[m_][n_] = __builtin_amdgcn_mfma_f32_16x16x32_bf16( \
              af_[m_][k_], bf_[n_][k_], acc[m_][n_], 0, 0, 0); \
    __builtin_amdgcn_s_setprio(0); \
  } while (0)

  // prologue: stage tile 0
  STAGE(0, 0);
  // K = 1024 -> 16 tiles of BK=64
  for (int t = 0; t < 16; ++t) {
    if (t + 1 < 16) {
      STAGE((t + 1) & 1, t + 1);                      // 8 vm-ops into other buf
      asm volatile("s_waitcnt vmcnt(8)" ::: "memory"); // tile t landed; t+1 in flight
    } else {
      asm volatile("s_waitcnt vmcnt(0)" ::: "memory"); // final tile
    }
    asm volatile("s_barrier" ::: "memory");            // all waves see tile t
    COMPUTE(t & 1);
    if (t + 1 < 16)
      asm volatile("s_barrier" ::: "memory");          // buf[(t)&1]... all done reading
  }
#undef STAGE
#undef COMPUTE

  // epilogue — C/D layout (m89/m91): col = lane&15, row = (lane>>4)*4 + reg
  const int rb = m0 + wr * 64 + l16 * 4;
  const int cb = n0 + wc * 64 + l15;
  if (MODE == 0) {
    float* o = (float*)Out;
#pragma unroll
    for (int m = 0; m < 4; m++)
#pragma unroll
      for (int n = 0; n < 4; n++)
#pragma unroll
        for (int r = 0; r < 4; r++)
          o[(size_t)(rb + m * 16 + r) * 1024 + cb + n * 16] = acc[m][n][r];
  } else if (n0 >= 2048) {
    // V third -> vt[(b*1024 + hd)][s], 4 consecutive s per lane packed as 8B
#pragma unroll
    for (int m = 0; m < 4; m++)
#pragma unroll
      for (int n = 0; n < 4; n++) {
        int row = rb + m * 16, col = cb + n * 16;
        int bb = row >> 11, s = row & 2047, hd = col - 2048;
        u16x4 pk = {f2bf(acc[m][n][0]), f2bf(acc[m][n][1]),
                    f2bf(acc[m][n][2]), f2bf(acc[m][n][3])};
        *(u16x4*)&vt[(size_t)(bb * 1024 + hd) * S_LEN + s] = pk;
      }
  } else {
    // q,k thirds: fused RoPE (+QSCALE on q). Pair (even,odd) cols live in
    // adjacent lanes -> one shfl_xor(1) exchanges partners.
    u16* qk = (u16*)Out;
    const bool isq = (n0 < 1024);
#pragma unroll
    for (int m = 0; m < 4; m++) {
      int row0 = rb + m * 16;
      int s0 = row0 & 2047;
#pragma unroll
      for (int n = 0; n < 4; n++) {
        int col = cb + n * 16;
        int fi = (col & 63) >> 1;
        bool odd = col & 1;
        f32x4 v = acc[m][n];
        f32x4 p;
#pragma unroll
        for (int r = 0; r < 4; r++) p[r] = __shfl_xor(v[r], 1);
#pragma unroll
        for (int r = 0; r < 4; r++) {
          float2 cs = tab[(s0 + r) * 32 + fi];
          float xe = odd ? p[r] : v[r];
          float xo = odd ? v[r] : p[r];
          float o = odd ? (xe * cs.y + xo * cs.x) : (xe * cs.x - xo * cs.y);
          if (isq) o *= QSCALE;
          qk[(size_t)(row0 + r) * 2048 + col] = f2bf(o);
        }
      }
    }
  }
}

// ---------------- causal flash attention, fixed-max exp2 softmax ----------------
// grid: (bh=32, j=32), qt = 31-j (LPT). 4 waves, wave w owns q rows
// [q0+16w, +16). KVBLK=64. lsum via MFMA-with-ones.
__global__ __launch_bounds__(256) void k_attn(const u16* __restrict__ qk,
                                              const u16* __restrict__ vt,
                                              u16* __restrict__ aout) {
  __shared__ alignas(16) u16 Ks[64 * 64];     // K tile [kv][d], swizzled
  __shared__ alignas(16) u16 Vs[64 * 64];     // V^T tile [d][kv], swizzled
  __shared__ alignas(16) u16 Ps[4][16 * 64];  // per-wave P [q][kv], swizzled
  const int tid = threadIdx.x, lane = tid & 63, w = tid >> 6;
  const int l15 = lane & 15, l16 = lane >> 4;
  const int qt = 31 - blockIdx.y;
  const int q0 = qt * 64;
  const int bh = blockIdx.x, b = bh >> 4, h = bh & 15;
  const u16* qbase = qk + (size_t)b * S_LEN * 2048 + h * 64;
  const u16* kbase = qbase + 1024;
  const u16* vbase = vt + (size_t)bh * 64 * S_LEN;
  const int wq0 = q0 + w * 16;

  bf16x8 qa[2];
#pragma unroll
  for (int kb = 0; kb < 2; kb++)
    qa[kb] = *(const bf16x8*)&qbase[(size_t)(wq0 + l15) * 2048 + kb * 32 + l16 * 8];

  bf16x8 vone;
#pragma unroll
  for (int j = 0; j < 8; j++) vone[j] = (__bf16)1.0f;

  f32x4 osum[4] = {};
  f32x4 osl = {};  // row-sum of P (all 16 cols identical)

  const int nt = qt + 1;  // 64-wide kv tiles
  const int srow = tid >> 2, scg = (tid & 3) * 16;
  u32x4 kr0, kr1, vr0, vr1;
  {
    const u16* kp = kbase + (size_t)srow * 2048 + scg;
    kr0 = *(const u32x4*)kp; kr1 = *(const u32x4*)(kp + 8);
    const u16* vp = vbase + (size_t)srow * S_LEN + scg;
    vr0 = *(const u32x4*)vp; vr1 = *(const u32x4*)(vp + 8);
  }

  for (int t = 0; t < nt; t++) {
    const int kv0 = t * 64;
    __syncthreads();  // everyone done reading previous tile
    *(u32x4*)&Ks[swz(srow, scg)]     = kr0;
    *(u32x4*)&Ks[swz(srow, scg + 8)] = kr1;
    *(u32x4*)&Vs[swz(srow, scg)]     = vr0;
    *(u32x4*)&Vs[swz(srow, scg + 8)] = vr1;
    __syncthreads();  // tile ready
    if (t + 1 < nt) {  // register prefetch of next tile drains under compute
      const u16* kp = kbase + (size_t)(kv0 + 64 + srow) * 2048 + scg;
      kr0 = *(const u32x4*)kp; kr1 = *(const u32x4*)(kp + 8);
      const u16* vp = vbase + (size_t)srow * S_LEN + kv0 + 64 + scg;
      vr0 = *(const u32x4*)vp; vr1 = *(const u32x4*)(vp + 8);
    }

    // QK^T: 16 q rows x 64 kv per wave (Q pre-scaled by QSCALE)
    f32x4 sc[4];
#pragma unroll
    for (int n = 0; n < 4; n++) {
      bf16x8 kf0 = *(const bf16x8*)&Ks[swz(n * 16 + l15, l16 * 8)];
      bf16x8 kf1 = *(const bf16x8*)&Ks[swz(n * 16 + l15, 32 + l16 * 8)];
      f32x4 z = {0.f, 0.f, 0.f, 0.f};
      z = __builtin_amdgcn_mfma_f32_16x16x32_bf16(qa[0], kf0, z, 0, 0, 0);
      sc[n] = __builtin_amdgcn_mfma_f32_16x16x32_bf16(qa[1], kf1, z, 0, 0, 0);
    }

    // P = exp2(s - 16); causal mask only on the diagonal tile
    const bool diag = (t == nt - 1);
#pragma unroll
    for (int n = 0; n < 4; n++)
#pragma unroll
      for (int r = 0; r < 4; r++) {
        float s = sc[n][r];
        if (diag && (kv0 + n * 16 + l15 > wq0 + l16 * 4 + r)) s = -1e30f;
        float p = vexp2(s - 16.0f);
        Ps[w][swz(l16 * 4 + r, n * 16 + l15)] = f2bf(p);
      }

    // PV + row-sum: A = P (16q x 64kv), B^T = V^T. Same-wave LDS, no barrier.
#pragma unroll
    for (int ks = 0; ks < 2; ks++) {
      bf16x8 pa = *(const bf16x8*)&Ps[w][swz(l15, ks * 32 + l16 * 8)];
      osl = __builtin_amdgcn_mfma_f32_16x16x32_bf16(pa, vone, osl, 0, 0, 0);
#pragma unroll
      for (int n = 0; n < 4; n++) {
        bf16x8 vb = *(const bf16x8*)&Vs[swz(n * 16 + l15, ks * 32 + l16 * 8)];
        osum[n] = __builtin_amdgcn_mfma_f32_16x16x32_bf16(pa, vb, osum[n], 0, 0, 0);
      }
    }
  }

  f32x4 inv;
#pragma unroll
  for (int r = 0; r < 4; r++) inv[r] = 1.0f / osl[r];
  u16* ob = aout + (size_t)b * S_LEN * DMODEL + h * 64;
#pragma unroll
  for (int n = 0; n < 4; n++)
#pragma unroll
    for (int r = 0; r < 4; r++) {
      int s = wq0 + l16 * 4 + r;
      ob[(size_t)s * DMODEL + n * 16 + l15] = f2bf(osum[n][r] * inv[r]);
    }
}

extern "C" void kernel_launch(void* const* d_in, const int* in_sizes, int n_in,
                              void* d_out, int out_size, void* d_ws, size_t ws_size,
                              hipStream_t stream) {
  const float* x = (const float*)d_in[0];
  const int* pos = (const int*)d_in[1];
  const float* wqkv = (const float*)d_in[2];
  const float* wout = (const float*)d_in[3];
  float* out = (float*)d_out;
  char* ws = (char*)d_ws;

  // workspace layout (bytes) — ~50.9 MB total
  u16* qkb   = (u16*)(ws);                      // [4096][2048] q,k  16,777,216
  u16* vtb   = (u16*)(ws + 16777216);           // [2][16][64][2048]  8,388,608
  u16* aoutb = (u16*)(ws + 25165824);           // [4096][1024]       8,388,608
  u16* xb    = (u16*)(ws + 33554432);           //                    8,388,608
  u16* wqb   = (u16*)(ws + 41943040);           //                    6,291,456
  u16* wob   = (u16*)(ws + 48234496);           //                    2,097,152
  float2* tab = (float2*)(ws + 50331648);       // 2048*32*8   =      524,288
  (void)ws_size;

  k_cvt_all<<<4096, 256, 0, stream>>>(x, wqkv, wout, xb, wqb, wob);
  k_rope_tab<<<65536 / 256, 256, 0, stream>>>(pos, tab);

  // GEMM1: 32 x 24 = 768 blocks (3 full rounds), RoPE fused
  k_gemm<1><<<768, 256, 0, stream>>>(xb, wqb, qkb, vtb, tab, 24);

  dim3 ga(2 * NHEAD, S_LEN / 64);  // x = bh (fast, XCD spread), y = qtile slot
  k_attn<<<ga, 256, 0, stream>>>(qkb, vtb, aoutb);

  // GEMM2: 32 x 8 = 256 blocks (1 full round)
  k_gemm<0><<<256, 256, 0, stream>>>(aoutb, wob, out, nullptr, nullptr, 8);
}

// Round 7
// 102.229 us; speedup vs baseline: 1.0667x; 1.0667x over previous
//
#include <hip/hip_runtime.h>

typedef unsigned short u16;
typedef unsigned int u32;
typedef __attribute__((ext_vector_type(8))) __bf16 bf16x8;
typedef __attribute__((ext_vector_type(4))) float f32x4;
typedef __attribute__((ext_vector_type(4))) u32 u32x4;
typedef __attribute__((ext_vector_type(4))) u16 u16x4;

#define DEV __device__ __forceinline__

constexpr int S_LEN = 2048;
constexpr int DMODEL = 1024;
constexpr int NHEAD = 16;
constexpr int ROWS = 4096;   // B*S
// fold 1/sqrt(64) * log2(e) into Q so softmax is exp2(s - B), B = 16
constexpr float QSCALE = 0.125f * 1.4426950408889634f;

DEV u16 f2bf(float f) {
  union { float f; u32 u; } v; v.f = f;
  u32 u = v.u;
  u32 r = (u + 0x7fffu + ((u >> 16) & 1u)) >> 16;  // RNE
  return (u16)r;
}
DEV float vexp2(float x) {
#if __has_builtin(__builtin_amdgcn_exp2f)
  return __builtin_amdgcn_exp2f(x);
#else
  return exp2f(x);
#endif
}
// XOR swizzle for [rows][64] u16 LDS tiles (row stride 128B), 8-col granules
DEV int swz(int r, int c) { return r * 64 + (c ^ ((r & 7) << 3)); }

// ---------------- fused fp32 -> bf16 convert for x, w_qkv, w_out ----------------
__global__ __launch_bounds__(256) void k_cvt_all(const float* __restrict__ x,
                                                 const float* __restrict__ wq,
                                                 const float* __restrict__ wo,
                                                 u16* __restrict__ xb,
                                                 u16* __restrict__ wqb,
                                                 u16* __restrict__ wob) {
  int i = blockIdx.x * 256 + threadIdx.x;  // 1048576 total (x8 elems)
  const float* in; u16* out; int off;
  if (i < 524288)       { in = x;  out = xb;  off = i; }
  else if (i < 917504)  { in = wq; out = wqb; off = i - 524288; }
  else                  { in = wo; out = wob; off = i - 917504; }
  const float4* p4 = (const float4*)in;
  float4 a = p4[2 * off], b = p4[2 * off + 1];
  alignas(16) u16 r[8] = {f2bf(a.x), f2bf(a.y), f2bf(a.z), f2bf(a.w),
                          f2bf(b.x), f2bf(b.y), f2bf(b.z), f2bf(b.w)};
  *(u32x4*)(out + 8 * off) = *(const u32x4*)r;
}

// ---------------- RoPE cos/sin table: [S][32] float2 (cos, sin) ----------------
__global__ __launch_bounds__(256) void k_rope_tab(const int* __restrict__ pos,
                                                  float2* __restrict__ tab) {
  int t = blockIdx.x * 256 + threadIdx.x;  // S*32 = 65536
  int s = t >> 5, fi = t & 31;
  float p = (float)pos[s];
  float invf = expf(-(float)fi * 0.28782313662425572f);  // 10000^(-fi/32)
  float ang = p * invf;
  tab[t] = float2{cosf(ang), sinf(ang)};
}

// ================= GEMM: BM x 128 tile, BK=32, reg-staged, 1 barrier/iter =====
// All waits compiler-visible: global->VGPR loads (auto counted vmcnt before the
// dependent ds_write), ds ops (auto lgkm). Only a raw s_barrier per iter; global
// loads for tile t+2 stay in flight across it. 4 waves (2x2), wave (BM/2)x64.
// VGPR<=128 (launch_bounds(256,4)) -> 4 blocks/CU at 512-VGPR/SIMD pool.
// MODE 1 (BM=128): cols<2048 -> RoPE(+QSCALE on q) fused -> bf16 qk[row][2048];
//                  cols>=2048 -> V^T bf16 vt[(b*1024+hd)][s].
// MODE 0 (BM=64): fp32 out [M][1024].
template <int BM, int MODE>
__global__ __launch_bounds__(256, 4) void k_gemm(const u16* __restrict__ A,
                                                 const u16* __restrict__ Bw,
                                                 void* __restrict__ Out,
                                                 u16* __restrict__ vt,
                                                 const float2* __restrict__ tab,
                                                 int NB) {
  constexpr int MR = BM / 32;   // A frags per wave (m dir)
  constexpr int NA = BM / 64;   // A stage granules per thread
  __shared__ alignas(16) u16 As[2][BM * 32];
  __shared__ alignas(16) u16 Bs[2][128 * 32];
  const int tid = threadIdx.x, lane = tid & 63;
  const int w = tid >> 6, wr = w >> 1, wc = w & 1;
  const int l15 = lane & 15, l16 = lane >> 4;
  // bijective XCD swizzle (grid multiple of 8)
  const int cpx = gridDim.x >> 3;
  const int wg = (blockIdx.x & 7) * cpx + (blockIdx.x >> 3);
  const int mb = wg / NB, nb = wg - mb * NB;
  const int m0 = mb * BM, n0 = nb * 128;

  // staging map: granule g of a [R][32] tile: row = g>>2, col = (g&3)*8.
  // thread covers A granules {tid (+256 if BM=128)}, B granules {tid, tid+256}.
  const int grow = tid >> 2, gc = tid & 3;
  const u16* aP = A + (size_t)(m0 + grow) * 1024 + gc * 8;
  const u16* bP = Bw + (size_t)(n0 + grow) * 1024 + gc * 8;
  // LDS write idx with granule XOR (row&3); (row+64)&3 == row&3 -> +64*32
  const int wrI = grow * 32 + ((gc ^ (grow & 3)) << 3);

  u32x4 ra0, ra1, rb0, rb1;
#define LOADT(t) do { \
    ra0 = *(const u32x4*)(aP + (t) * 32); \
    if (NA == 2) ra1 = *(const u32x4*)(aP + 65536 + (t) * 32); \
    rb0 = *(const u32x4*)(bP + (t) * 32); \
    rb1 = *(const u32x4*)(bP + 65536 + (t) * 32); \
  } while (0)
#define WRITET(bufc) do { \
    *(u32x4*)&As[bufc][wrI] = ra0; \
    if (NA == 2) *(u32x4*)&As[bufc][wrI + 2048] = ra1; \
    *(u32x4*)&Bs[bufc][wrI] = rb0; \
    *(u32x4*)&Bs[bufc][wrI + 2048] = rb1; \
  } while (0)

  f32x4 acc[MR][4] = {};
  const int x3 = l15 & 3;

#define COMPUTE(bufc) do { \
    bf16x8 af[MR]; \
    _Pragma("unroll") \
    for (int m_ = 0; m_ < MR; m_++) \
      af[m_] = *(const bf16x8*)&As[bufc][(wr * (BM / 2) + m_ * 16 + l15) * 32 + \
                                         (((l16 ^ x3)) << 3)]; \
    __builtin_amdgcn_s_setprio(1); \
    _Pragma("unroll") \
    for (int n_ = 0; n_ < 4; n_++) { \
      bf16x8 bb = *(const bf16x8*)&Bs[bufc][(wc * 64 + n_ * 16 + l15) * 32 + \
                                            (((l16 ^ x3)) << 3)]; \
      _Pragma("unroll") \
      for (int m_ = 0; m_ < MR; m_++) \
        acc[m_][n_] = __builtin_amdgcn_mfma_f32_16x16x32_bf16(af[m_], bb, acc[m_][n_], 0, 0, 0); \
    } \
    __builtin_amdgcn_s_setprio(0); \
  } while (0)

#define BAR() do { \
    asm volatile("s_waitcnt lgkmcnt(0)" ::: "memory"); \
    __builtin_amdgcn_s_barrier(); \
  } while (0)

  // prologue: tile0 -> LDS buf0; tile1 -> regs (in flight / landed)
  LOADT(0);
  WRITET(0);
  LOADT(1);
  BAR();

  // K = 1024 -> 32 tiles of BK=32
  for (int t = 0; t < 32; ++t) {
    COMPUTE(t & 1);
    if (t + 1 < 32) WRITET((t + 1) & 1);  // vmcnt wait on regs inserted by compiler
    if (t + 2 < 32) LOADT(t + 2);          // stays in flight across the barrier
    BAR();
  }
#undef LOADT
#undef WRITET
#undef COMPUTE
#undef BAR

  // epilogue — C/D layout (m89/m91): col = lane&15, row = (lane>>4)*4 + reg
  const int rb = m0 + wr * (BM / 2) + l16 * 4;
  const int cb = n0 + wc * 64 + l15;
  if (MODE == 0) {
    float* o = (float*)Out;
#pragma unroll
    for (int m = 0; m < MR; m++)
#pragma unroll
      for (int n = 0; n < 4; n++)
#pragma unroll
        for (int r = 0; r < 4; r++)
          o[(size_t)(rb + m * 16 + r) * 1024 + cb + n * 16] = acc[m][n][r];
  } else if (n0 >= 2048) {
    // V third -> vt[(b*1024 + hd)][s], 4 consecutive s per lane packed as 8B
#pragma unroll
    for (int m = 0; m < MR; m++)
#pragma unroll
      for (int n = 0; n < 4; n++) {
        int row = rb + m * 16, col = cb + n * 16;
        int bb = row >> 11, s = row & 2047, hd = col - 2048;
        u16x4 pk = {f2bf(acc[m][n][0]), f2bf(acc[m][n][1]),
                    f2bf(acc[m][n][2]), f2bf(acc[m][n][3])};
        *(u16x4*)&vt[(size_t)(bb * 1024 + hd) * S_LEN + s] = pk;
      }
  } else {
    // q,k thirds: fused RoPE (+QSCALE on q). Pair (even,odd) cols live in
    // adjacent lanes -> one shfl_xor(1) exchanges partners.
    u16* qk = (u16*)Out;
    const bool isq = (n0 < 1024);
#pragma unroll
    for (int m = 0; m < MR; m++) {
      int row0 = rb + m * 16;
      int s0 = row0 & 2047;
#pragma unroll
      for (int n = 0; n < 4; n++) {
        int col = cb + n * 16;
        int fi = (col & 63) >> 1;
        bool odd = col & 1;
        f32x4 v = acc[m][n];
        f32x4 p;
#pragma unroll
        for (int r = 0; r < 4; r++) p[r] = __shfl_xor(v[r], 1);
#pragma unroll
        for (int r = 0; r < 4; r++) {
          float2 cs = tab[(s0 + r) * 32 + fi];
          float xe = odd ? p[r] : v[r];
          float xo = odd ? v[r] : p[r];
          float o = odd ? (xe * cs.y + xo * cs.x) : (xe * cs.x - xo * cs.y);
          if (isq) o *= QSCALE;
          qk[(size_t)(row0 + r) * 2048 + col] = f2bf(o);
        }
      }
    }
  }
}

// ---------------- causal flash attention, fixed-max exp2 softmax ----------------
// grid: (bh=32, j=32), qt = 31-j (LPT). 4 waves, wave w owns q rows
// [q0+16w, +16). KVBLK=64. lsum via MFMA-with-ones.
__global__ __launch_bounds__(256) void k_attn(const u16* __restrict__ qk,
                                              const u16* __restrict__ vt,
                                              u16* __restrict__ aout) {
  __shared__ alignas(16) u16 Ks[64 * 64];     // K tile [kv][d], swizzled
  __shared__ alignas(16) u16 Vs[64 * 64];     // V^T tile [d][kv], swizzled
  __shared__ alignas(16) u16 Ps[4][16 * 64];  // per-wave P [q][kv], swizzled
  const int tid = threadIdx.x, lane = tid & 63, w = tid >> 6;
  const int l15 = lane & 15, l16 = lane >> 4;
  const int qt = 31 - blockIdx.y;
  const int q0 = qt * 64;
  const int bh = blockIdx.x, b = bh >> 4, h = bh & 15;
  const u16* qbase = qk + (size_t)b * S_LEN * 2048 + h * 64;
  const u16* kbase = qbase + 1024;
  const u16* vbase = vt + (size_t)bh * 64 * S_LEN;
  const int wq0 = q0 + w * 16;

  bf16x8 qa[2];
#pragma unroll
  for (int kb = 0; kb < 2; kb++)
    qa[kb] = *(const bf16x8*)&qbase[(size_t)(wq0 + l15) * 2048 + kb * 32 + l16 * 8];

  bf16x8 vone;
#pragma unroll
  for (int j = 0; j < 8; j++) vone[j] = (__bf16)1.0f;

  f32x4 osum[4] = {};
  f32x4 osl = {};  // row-sum of P (all 16 cols identical)

  const int nt = qt + 1;  // 64-wide kv tiles
  const int srow = tid >> 2, scg = (tid & 3) * 16;
  u32x4 kr0, kr1, vr0, vr1;
  {
    const u16* kp = kbase + (size_t)srow * 2048 + scg;
    kr0 = *(const u32x4*)kp; kr1 = *(const u32x4*)(kp + 8);
    const u16* vp = vbase + (size_t)srow * S_LEN + scg;
    vr0 = *(const u32x4*)vp; vr1 = *(const u32x4*)(vp + 8);
  }

  for (int t = 0; t < nt; t++) {
    const int kv0 = t * 64;
    __syncthreads();  // everyone done reading previous tile
    *(u32x4*)&Ks[swz(srow, scg)]     = kr0;
    *(u32x4*)&Ks[swz(srow, scg + 8)] = kr1;
    *(u32x4*)&Vs[swz(srow, scg)]     = vr0;
    *(u32x4*)&Vs[swz(srow, scg + 8)] = vr1;
    __syncthreads();  // tile ready
    if (t + 1 < nt) {  // register prefetch of next tile drains under compute
      const u16* kp = kbase + (size_t)(kv0 + 64 + srow) * 2048 + scg;
      kr0 = *(const u32x4*)kp; kr1 = *(const u32x4*)(kp + 8);
      const u16* vp = vbase + (size_t)srow * S_LEN + kv0 + 64 + scg;
      vr0 = *(const u32x4*)vp; vr1 = *(const u32x4*)(vp + 8);
    }

    // QK^T: 16 q rows x 64 kv per wave (Q pre-scaled by QSCALE)
    f32x4 sc[4];
#pragma unroll
    for (int n = 0; n < 4; n++) {
      bf16x8 kf0 = *(const bf16x8*)&Ks[swz(n * 16 + l15, l16 * 8)];
      bf16x8 kf1 = *(const bf16x8*)&Ks[swz(n * 16 + l15, 32 + l16 * 8)];
      f32x4 z = {0.f, 0.f, 0.f, 0.f};
      z = __builtin_amdgcn_mfma_f32_16x16x32_bf16(qa[0], kf0, z, 0, 0, 0);
      sc[n] = __builtin_amdgcn_mfma_f32_16x16x32_bf16(qa[1], kf1, z, 0, 0, 0);
    }

    // P = exp2(s - 16); causal mask only on the diagonal tile
    const bool diag = (t == nt - 1);
#pragma unroll
    for (int n = 0; n < 4; n++)
#pragma unroll
      for (int r = 0; r < 4; r++) {
        float s = sc[n][r];
        if (diag && (kv0 + n * 16 + l15 > wq0 + l16 * 4 + r)) s = -1e30f;
        float p = vexp2(s - 16.0f);
        Ps[w][swz(l16 * 4 + r, n * 16 + l15)] = f2bf(p);
      }

    // PV + row-sum: A = P (16q x 64kv), B^T = V^T. Same-wave LDS, no barrier.
#pragma unroll
    for (int ks = 0; ks < 2; ks++) {
      bf16x8 pa = *(const bf16x8*)&Ps[w][swz(l15, ks * 32 + l16 * 8)];
      osl = __builtin_amdgcn_mfma_f32_16x16x32_bf16(pa, vone, osl, 0, 0, 0);
#pragma unroll
      for (int n = 0; n < 4; n++) {
        bf16x8 vb = *(const bf16x8*)&Vs[swz(n * 16 + l15, ks * 32 + l16 * 8)];
        osum[n] = __builtin_amdgcn_mfma_f32_16x16x32_bf16(pa, vb, osum[n], 0, 0, 0);
      }
    }
  }

  f32x4 inv;
#pragma unroll
  for (int r = 0; r < 4; r++) inv[r] = 1.0f / osl[r];
  u16* ob = aout + (size_t)b * S_LEN * DMODEL + h * 64;
#pragma unroll
  for (int n = 0; n < 4; n++)
#pragma unroll
    for (int r = 0; r < 4; r++) {
      int s = wq0 + l16 * 4 + r;
      ob[(size_t)s * DMODEL + n * 16 + l15] = f2bf(osum[n][r] * inv[r]);
    }
}

extern "C" void kernel_launch(void* const* d_in, const int* in_sizes, int n_in,
                              void* d_out, int out_size, void* d_ws, size_t ws_size,
                              hipStream_t stream) {
  const float* x = (const float*)d_in[0];
  const int* pos = (const int*)d_in[1];
  const float* wqkv = (const float*)d_in[2];
  const float* wout = (const float*)d_in[3];
  float* out = (float*)d_out;
  char* ws = (char*)d_ws;

  // workspace layout (bytes) — ~50.9 MB total
  u16* qkb   = (u16*)(ws);                      // [4096][2048] q,k  16,777,216
  u16* vtb   = (u16*)(ws + 16777216);           // [2][16][64][2048]  8,388,608
  u16* aoutb = (u16*)(ws + 25165824);           // [4096][1024]       8,388,608
  u16* xb    = (u16*)(ws + 33554432);           //                    8,388,608
  u16* wqb   = (u16*)(ws + 41943040);           //                    6,291,456
  u16* wob   = (u16*)(ws + 48234496);           //                    2,097,152
  float2* tab = (float2*)(ws + 50331648);       // 2048*32*8   =      524,288
  (void)ws_size;

  k_cvt_all<<<4096, 256, 0, stream>>>(x, wqkv, wout, xb, wqb, wob);
  k_rope_tab<<<65536 / 256, 256, 0, stream>>>(pos, tab);

  // GEMM1: 32 mb x 24 nb = 768 blocks, tile 128x128, RoPE fused
  k_gemm<128, 1><<<768, 256, 0, stream>>>(xb, wqb, qkb, vtb, tab, 24);

  dim3 ga(2 * NHEAD, S_LEN / 64);  // x = bh (fast, XCD spread), y = qtile slot
  k_attn<<<ga, 256, 0, stream>>>(qkb, vtb, aoutb);

  // GEMM2: 64 mb x 8 nb = 512 blocks, tile 64x128
  k_gemm<64, 0><<<512, 256, 0, stream>>>(aoutb, wob, out, nullptr, nullptr, 8);
}